// Round 9
// baseline (3775.344 us; speedup 1.0000x reference)
//
#include <hip/hip_runtime.h>
#include <hip/hip_bf16.h>

// Problem dims (fixed by reference). All global I/O is fp32.
#define BATCH 1024
#define DLAT  512
#define HHID  1024
#define TPTS  64
#define BD    (BATCH * DLAT)     // 524288

// Cooperative decomposition: 16 row-groups (64 rows) x 16 col-groups.
// 256 blocks @ ~131 KB LDS -> exactly 1 block/CU -> exactly 32 blocks/XCD.
// LDS > 80 KB is LOAD-BEARING: it forces 1 block/CU so each XCD hosts exactly
// 32 blocks, which is what makes the XCD-local flag/exchange protocol sound.
#define NBLK 256
#define NTHR 512                 // 8 waves
#define RGN  16                  // blocks per row-group (and # col groups)

// History (do not retry):
//  - W1-in-registers: toolchain caps at 128 VGPRs (launch_bounds & waves_per_eu
//    both ignored) -> spills, -24%.  (rounds 3-6)
//  - 32x32 MFMA + split-K: flat vs 16x16 (round 8) -> not operand-BW-bound.
//  - Hand-rolled barrier signal/poll: hung (round 3).
// Round 9: replace the 2 per-stage rg_barriers (16-way serialized RMW on one
// line + tid0-only poll + 2 syncthreads each, ~3.5us/stage) with per-block
// GENERATION FLAGS: one writer per flag (uncontended atomicAdd), all 16 flags
// polled in parallel by lanes (one vector AGENT atomic load + __all).
// zf is DOUBLE-BUFFERED (slot g&1) for WAR safety; Hf single (safe because
// phase A(g) waits all 16 zflags(g), each published after that block's full
// phase B(g-1) incl. its Hf reads).

typedef __attribute__((ext_vector_type(8))) short short8;  // 8 bf16 (4 VGPRs)
typedef __attribute__((ext_vector_type(4))) float f32x4;   // MFMA C/D frag

__device__ __forceinline__ short f2bf(float x) {
    __hip_bfloat16 h = __float2bfloat16(x);
    return __builtin_bit_cast(short, h);
}
__device__ __forceinline__ float fast_tanh(float x) {
    x = fminf(9.f, fmaxf(-9.f, x));
    const float e = __expf(2.f * x);
    return (e - 1.f) / (e + 1.f);
}

// Wait until all 16 flags of this row-group reach generation `need`.
// fp = per-lane flag pointer (lanes 0-15 cover the 16 blocks; 16-63 replicate).
// Poll = AGENT-scope atomic load (L1-bypassing, round-2-proven primitive).
// Acquire = buffer_inv (per-CU L1 invalidate only; NO device fence).
__device__ __forceinline__ void wait_flags(const int* fp, int need) {
    while (true) {
        const int v = __hip_atomic_load(fp, __ATOMIC_RELAXED,
                                        __HIP_MEMORY_SCOPE_AGENT);
        if (__all(v >= need)) break;
        __builtin_amdgcn_s_sleep(2);
    }
    asm volatile("buffer_inv\n\ts_waitcnt vmcnt(0)" ::: "memory");
}

// ---------------------------------------------------------------------------
// block(rg,cg): rows [rg*64,+64), phase-A H-cols [cg*64,+64), phase-B z-cols
// [cg*32,+32).  rg is XCD-local by construction (slot from real XCC_ID).
// W1 slice [512x64] + W2 slice [1024x32] in LDS all 252 stages.
// Exchange (bf16 MFMA-A fragment order, XCD-L2 resident):
//   zf[2 slots]: per slot [64 row-tiles][16 k-tiles][64 lanes][8]  (1 MB each)
//   Hf:          [64 row-tiles][32 k-tiles][64 lanes][8]           (2 MB)
// Direct 2B epilogue stores (round-7, bank-conflict-free, no staging).
// mfma_f32_16x16x32_bf16 layouts (m89/m120-verified):
//   A[m=lane&15][k=(lane>>4)*8+j], B[k=(lane>>4)*8+j][n=lane&15]
//   C/D: col=lane&15, row=(lane>>4)*4+reg
// ---------------------------------------------------------------------------
__global__ __launch_bounds__(NTHR) void ode_coop(
    const float* __restrict__ z0, const float* __restrict__ t,
    const float* __restrict__ W1, const float* __restrict__ b1,
    const float* __restrict__ W2, const float* __restrict__ b2,
    short* __restrict__ zf, short* __restrict__ Hf,
    int* __restrict__ zfl, int* __restrict__ hfl,
    int* __restrict__ xcnt, float* __restrict__ traj)
{
    __shared__ __align__(16) short W1L[4 * 16 * 64 * 8];  // 64 KB [ct][kt][lane][j]
    __shared__ __align__(16) short W2L[2 * 32 * 64 * 8];  // 64 KB [ct2][kt2][lane][j]
    __shared__ float b1L[64];
    __shared__ float b2L[32];
    __shared__ int slotS;

    const int tid  = threadIdx.x;
    const int lane = tid & 63;
    const int w    = tid >> 6;       // wave 0..7
    const int q    = lane >> 4;
    const int cl   = lane & 15;

    // ---- role assignment from the REAL XCD id (same-XCD rg by construction) ----
    unsigned int xcc;
    asm("s_getreg_b32 %0, hwreg(HW_REG_XCC_ID)" : "=s"(xcc));
    xcc &= 7u;
    if (tid == 0) slotS = atomicAdd(&xcnt[xcc], 1);
    __syncthreads();
    const int slot = slotS & 31;                   // 0..31 within this XCD
    const int rg   = (int)xcc * 2 + (slot >> 4);   // 0..15 row-group (XCD-local)
    const int cg   = slot & 15;                    // 0..15 col-group

    // flags: 16 per rg, spaced 4 ints (16 B)
    int* zflg = zfl + rg * 64;
    int* hflg = hfl + rg * 64;
    int* zown = zflg + cg * 4;
    int* hown = hflg + cg * 4;
    const int* zpoll = zflg + (lane & 15) * 4;
    const int* hpoll = hflg + (lane & 15) * 4;

    // ---- one-time: weight slices fp32 -> bf16 fragment order -> LDS ----
    for (int i = tid; i < 4 * 16 * 64; i += NTHR) {
        const int ct = i >> 10, kt = (i >> 6) & 15, l = i & 63;
        const int k0 = kt * 32 + (l >> 4) * 8;
        const int n  = cg * 64 + ct * 16 + (l & 15);
        short8 v;
#pragma unroll
        for (int j = 0; j < 8; ++j) v[j] = f2bf(W1[(size_t)(k0 + j) * HHID + n]);
        *(short8*)&W1L[i * 8] = v;
    }
    for (int i = tid; i < 2 * 32 * 64; i += NTHR) {
        const int ct = i >> 11, kt = (i >> 6) & 31, l = i & 63;
        const int k0 = kt * 32 + (l >> 4) * 8;
        const int n  = cg * 32 + ct * 16 + (l & 15);
        short8 v;
#pragma unroll
        for (int j = 0; j < 8; ++j) v[j] = f2bf(W2[(size_t)(k0 + j) * DLAT + n]);
        *(short8*)&W2L[i * 8] = v;
    }
    if (tid < 64)      b1L[tid]      = b1[cg * 64 + tid];
    else if (tid < 96) b2L[tid - 64] = b2[cg * 32 + (tid - 64)];

    // ---- ownership (round-7 layout, verbatim) ----
    const int rt   = w >> 1;
    const int c0   = (w & 1) * 2;
    const int ct2b = w & 1;
    const int rowb = rg * 64 + rt * 16 + q * 4;     // + reg = global batch row
    const int nb   = cg * 32 + ct2b * 16 + cl;      // global z col
    const int clb  = ct2b * 16 + cl;                // local z col 0..31

    const size_t zbase = ((size_t)(rg * 4 + rt) * 16 + cg) * 512 +
                         (size_t)(((clb >> 3) * 16 + q * 4) * 8 + (clb & 7));
    size_t hbase[2];
#pragma unroll
    for (int c = 0; c < 2; ++c) {
        const int colc = (c0 + c) * 16 + cl;
        hbase[c] = ((size_t)(rg * 4 + rt) * 32 + cg * 2 + (colc >> 5)) * 512 +
                   (size_t)((((colc & 31) >> 3) * 16 + q * 4) * 8 + (colc & 7));
    }

    short* zf0 = zf;
    short* zf1 = zf + 524288;       // second 1 MB slot

    float zreg[4], kacc[4];
#pragma unroll
    for (int reg = 0; reg < 4; ++reg) {
        const float zv = z0[(size_t)(rowb + reg) * DLAT + nb];
        zreg[reg] = zv;
        traj[(size_t)(rowb + reg) * DLAT + nb] = zv;    // traj[0] exact fp32
        zf1[zbase + reg * 8] = f2bf(zv);                // gen 1 -> slot 1
    }
    __syncthreads();                    // drain init stores (vmcnt(0) per wave)
    if (tid == 0) atomicAdd(zown, 1);   // publish z generation 1

    const size_t zrowoff = (size_t)(rg * 4 + rt) * 8192 + lane * 8;
    const short* hrow = Hf + (size_t)(rg * 4 + rt) * 16384 + lane * 8;
    const short* w1p  = &W1L[c0 * 8192 + lane * 8];
    const short* w2p  = &W2L[ct2b * 16384 + lane * 8];

    int g = 1;                          // RK4-stage generation, 1..252
    for (int step = 0; step < TPTS - 1; ++step) {
        const float dt = t[step + 1] - t[step];

        // traj[step] hoisted: HBM stores retire under phase A, not in a drain
        if (step > 0) {
#pragma unroll
            for (int reg = 0; reg < 4; ++reg)
                traj[(size_t)step * BD + (size_t)(rowb + reg) * DLAT + nb] =
                    zreg[reg];
        }

#pragma unroll
        for (int stage = 0; stage < 4; ++stage) {
            // ============== phase A: H = tanh(z @ W1slice + b1) ==============
            wait_flags(zpoll, g);                       // z gen g available
            {
                const short* zrow = ((g & 1) ? zf1 : zf0) + zrowoff;
                f32x4 acc0 = {0.f, 0.f, 0.f, 0.f};
                f32x4 acc1 = {0.f, 0.f, 0.f, 0.f};
#pragma unroll
                for (int kt = 0; kt < 16; ++kt) {
                    const short8 a  = *(const short8*)(zrow + kt * 512);
                    const short8 bA = *(const short8*)(w1p + kt * 512);
                    const short8 bB = *(const short8*)(w1p + 8192 + kt * 512);
                    acc0 = __builtin_amdgcn_mfma_f32_16x16x32_bf16(a, bA, acc0, 0, 0, 0);
                    acc1 = __builtin_amdgcn_mfma_f32_16x16x32_bf16(a, bB, acc1, 0, 0, 0);
                }
#pragma unroll
                for (int c = 0; c < 2; ++c) {
                    const int   cloc = (c0 + c) * 16 + cl;
                    const float bb   = b1L[cloc];
                    const f32x4 av   = c ? acc1 : acc0;
#pragma unroll
                    for (int reg = 0; reg < 4; ++reg)
                        Hf[hbase[c] + reg * 8] = f2bf(fast_tanh(av[reg] + bb));
                }
            }
            __syncthreads();                    // drain Hf stores (all waves)
            if (tid == 0) atomicAdd(hown, 1);   // publish H generation g

            // ============ phase B: kv = H @ W2slice + b2 ; RK4 update ========
            wait_flags(hpoll, g);                       // H gen g available
            {
                f32x4 acce = {0.f, 0.f, 0.f, 0.f};
                f32x4 acco = {0.f, 0.f, 0.f, 0.f};
#pragma unroll
                for (int kt = 0; kt < 32; kt += 2) {
                    const short8 a0  = *(const short8*)(hrow + kt * 512);
                    const short8 a1  = *(const short8*)(hrow + kt * 512 + 512);
                    const short8 bb0 = *(const short8*)(w2p + kt * 512);
                    const short8 bb1 = *(const short8*)(w2p + kt * 512 + 512);
                    acce = __builtin_amdgcn_mfma_f32_16x16x32_bf16(a0, bb0, acce, 0, 0, 0);
                    acco = __builtin_amdgcn_mfma_f32_16x16x32_bf16(a1, bb1, acco, 0, 0, 0);
                }
                const float bb = b2L[clb];
                short* zw = (((g + 1) & 1) ? zf1 : zf0);
#pragma unroll
                for (int reg = 0; reg < 4; ++reg) {
                    const float kv = acce[reg] + acco[reg] + bb;
                    float znext;
                    if (stage == 0) {
                        kacc[reg] = kv;        znext = zreg[reg] + 0.5f * dt * kv;
                    } else if (stage == 1) {
                        kacc[reg] += 2.f * kv; znext = zreg[reg] + 0.5f * dt * kv;
                    } else if (stage == 2) {
                        kacc[reg] += 2.f * kv; znext = zreg[reg] + dt * kv;
                    } else {
                        zreg[reg] += (dt * (1.f / 6.f)) * (kacc[reg] + kv);
                        znext = zreg[reg];
                    }
                    zw[zbase + reg * 8] = f2bf(znext);   // z gen g+1 -> slot (g+1)&1
                }
            }
            __syncthreads();                    // drain zf stores (all waves)
            if (tid == 0) atomicAdd(zown, 1);   // publish z generation g+1
            ++g;
        }
    }

    // final state: traj[TPTS-1] = z_{63}
#pragma unroll
    for (int reg = 0; reg < 4; ++reg)
        traj[(size_t)(TPTS - 1) * BD + (size_t)(rowb + reg) * DLAT + nb] =
            zreg[reg];
}

// ---------------------------------------------------------------------------
extern "C" void kernel_launch(void* const* d_in, const int* in_sizes, int n_in,
                              void* d_out, int out_size, void* d_ws, size_t ws_size,
                              hipStream_t stream)
{
    (void)in_sizes; (void)n_in; (void)out_size; (void)ws_size;

    const float* z0 = (const float*)d_in[0];
    const float* t  = (const float*)d_in[1];
    const float* W1 = (const float*)d_in[2];
    const float* b1 = (const float*)d_in[3];
    const float* W2 = (const float*)d_in[4];
    const float* b2 = (const float*)d_in[5];
    float*       traj = (float*)d_out;

    // Workspace: zf 2x1MB | Hf 2MB | zflags 4KB | hflags 4KB | xcnt 32B
    short* zf   = (short*)d_ws;
    short* Hf   = (short*)((char*)d_ws + (2u << 20));
    int*   zfl  = (int*)((char*)d_ws + (4u << 20));
    int*   hfl  = (int*)((char*)d_ws + (4u << 20) + 4096);
    int*   xcnt = (int*)((char*)d_ws + (4u << 20) + 8192);

    hipMemsetAsync(zfl, 0, 8192 + 32, stream);

    void* args[] = {&z0, &t, &W1, &b1, &W2, &b2, &zf, &Hf, &zfl, &hfl, &xcnt, &traj};
    hipLaunchCooperativeKernel((const void*)ode_coop, dim3(NBLK), dim3(NTHR),
                               args, 0, stream);
}

// Round 10
// 1408.419 us; speedup vs baseline: 2.6806x; 2.6806x over previous
//
#include <hip/hip_runtime.h>
#include <hip/hip_bf16.h>

// Problem dims (fixed by reference). All global I/O is fp32.
#define BATCH 1024
#define DLAT  512
#define HHID  1024
#define TPTS  64
#define BD    (BATCH * DLAT)     // 524288

// Cooperative decomposition: 16 row-groups (64 rows) x 16 col-groups.
// 256 blocks @ ~131 KB LDS -> exactly 1 block/CU -> exactly 32 blocks/XCD.
// LDS > 80 KB is LOAD-BEARING: it forces 1 block/CU so each XCD hosts exactly
// 32 blocks, which is what makes the XCD-local barrier/exchange sound.
#define NBLK 256
#define NTHR 512                 // 8 waves
#define RGN  16                  // blocks per row-group (and # col groups)

// History (do not retry):
//  - W1-in-registers: toolchain caps at 128 VGPRs -> spill, -24% (r3-6).
//  - 32x32 MFMA + split-K: flat vs 16x16 (r8) -> not operand-BW-bound.
//  - Hand-rolled asm signal/poll: hung (r3).
//  - FREE-RUNNING flag sync (every wave polls, decoupled phases): 2.7x
//    REGRESSION (r9). Sync must stay block-coupled: syncthreads -> signal ->
//    single-wave poll -> syncthreads -> buffer_inv.
// Round 10: keep round-2's coupled topology EXACTLY, but remove the 16-way
// serialized RMW chain: each block signals its OWN flag (16 independent
// 16B-spaced lines), wave-0 lanes 0-15 poll all 16 in parallel (one coalesced
// AGENT-scope load per iteration + __all).

typedef __attribute__((ext_vector_type(8))) short short8;  // 8 bf16 (4 VGPRs)
typedef __attribute__((ext_vector_type(4))) float f32x4;   // MFMA C/D frag

__device__ __forceinline__ short f2bf(float x) {
    __hip_bfloat16 h = __float2bfloat16(x);
    return __builtin_bit_cast(short, h);
}
__device__ __forceinline__ float fast_tanh(float x) {
    x = fminf(9.f, fmaxf(-9.f, x));
    const float e = __expf(2.f * x);
    return (e - 1.f) / (e + 1.f);
}

// Row-group barrier for 16 SAME-XCD blocks — round-2 coupled topology with
// uncontended per-block signal flags.
// Release: __syncthreads drains vmcnt(0) per wave (write-through L1 => all
//          stores in the shared XCD L2) before the signal.
// Signal:  tid0 atomicAdd(+1) on this block's OWN flag (no RMW contention).
// Poll:    wave 0 only; lanes 0-15 load the 16 flags (coalesced, AGENT scope,
//          L1-bypassing — round-2-proven primitive) until __all >= target.
// Acquire: __syncthreads releases all waves, then buffer_inv (L1-only inv;
//          NO device fence — round-1's 910 MB L2-writeback disaster).
__device__ __forceinline__ void rg_barrier(int* flg, int cg, int target, int tid)
{
    __syncthreads();             // s_waitcnt vmcnt(0) lgkmcnt(0) + s_barrier
    if (tid == 0) atomicAdd(flg + cg * 4, 1);
    if (tid < 16) {
        const int* fp = flg + tid * 4;
        int v;
        do {
            v = __hip_atomic_load(fp, __ATOMIC_RELAXED,
                                  __HIP_MEMORY_SCOPE_AGENT);
            if (!__all(v >= target)) __builtin_amdgcn_s_sleep(2);
            else break;
        } while (true);
    }
    __syncthreads();
    asm volatile("buffer_inv\n\ts_waitcnt vmcnt(0)" ::: "memory");  // L1 acquire
}

// ---------------------------------------------------------------------------
// block(rg,cg): rows [rg*64,+64), phase-A H-cols [cg*64,+64), phase-B z-cols
// [cg*32,+32).  rg is XCD-local by construction (slot from real XCC_ID).
// W1 slice [512x64] + W2 slice [1024x32] in LDS all 252 stages.
// Exchange (global, bf16 MFMA-A fragment order, XCD-L2 resident):
//   zf: [64 row-tiles][16 k-tiles][64 lanes][8]   (1 MB)
//   Hf: [64 row-tiles][32 k-tiles][64 lanes][8]   (2 MB)
// Direct 2B epilogue stores (round-7: bank-conflict 0, no staging).
// mfma_f32_16x16x32_bf16 layouts (m89/m120-verified):
//   A[m=lane&15][k=(lane>>4)*8+j], B[k=(lane>>4)*8+j][n=lane&15]
//   C/D: col=lane&15, row=(lane>>4)*4+reg
// ---------------------------------------------------------------------------
__global__ __launch_bounds__(NTHR) void ode_coop(
    const float* __restrict__ z0, const float* __restrict__ t,
    const float* __restrict__ W1, const float* __restrict__ b1,
    const float* __restrict__ W2, const float* __restrict__ b2,
    short* __restrict__ zf, short* __restrict__ Hf,
    int* __restrict__ fl, int* __restrict__ xcnt,
    float* __restrict__ traj)
{
    __shared__ __align__(16) short W1L[4 * 16 * 64 * 8];  // 64 KB [ct][kt][lane][j]
    __shared__ __align__(16) short W2L[2 * 32 * 64 * 8];  // 64 KB [ct2][kt2][lane][j]
    __shared__ float b1L[64];
    __shared__ float b2L[32];
    __shared__ int slotS;

    const int tid  = threadIdx.x;
    const int lane = tid & 63;
    const int w    = tid >> 6;       // wave 0..7
    const int q    = lane >> 4;
    const int cl   = lane & 15;

    // ---- role assignment from the REAL XCD id (same-XCD rg by construction) ----
    unsigned int xcc;
    asm("s_getreg_b32 %0, hwreg(HW_REG_XCC_ID)" : "=s"(xcc));
    xcc &= 7u;
    if (tid == 0) slotS = atomicAdd(&xcnt[xcc], 1);
    __syncthreads();
    const int slot = slotS & 31;                   // 0..31 within this XCD
    const int rg   = (int)xcc * 2 + (slot >> 4);   // 0..15 row-group (XCD-local)
    const int cg   = slot & 15;                    // 0..15 col-group
    int* flg = fl + rg * 64;                       // 16 flags x 16B for this rg

    // ---- one-time: weight slices fp32 -> bf16 fragment order -> LDS ----
    for (int i = tid; i < 4 * 16 * 64; i += NTHR) {
        const int ct = i >> 10, kt = (i >> 6) & 15, l = i & 63;
        const int k0 = kt * 32 + (l >> 4) * 8;
        const int n  = cg * 64 + ct * 16 + (l & 15);
        short8 v;
#pragma unroll
        for (int j = 0; j < 8; ++j) v[j] = f2bf(W1[(size_t)(k0 + j) * HHID + n]);
        *(short8*)&W1L[i * 8] = v;
    }
    for (int i = tid; i < 2 * 32 * 64; i += NTHR) {
        const int ct = i >> 11, kt = (i >> 6) & 31, l = i & 63;
        const int k0 = kt * 32 + (l >> 4) * 8;
        const int n  = cg * 32 + ct * 16 + (l & 15);
        short8 v;
#pragma unroll
        for (int j = 0; j < 8; ++j) v[j] = f2bf(W2[(size_t)(k0 + j) * DLAT + n]);
        *(short8*)&W2L[i * 8] = v;
    }
    if (tid < 64)      b1L[tid]      = b1[cg * 64 + tid];
    else if (tid < 96) b2L[tid - 64] = b2[cg * 32 + (tid - 64)];

    // ---- ownership (round-7 layout, verbatim) ----
    const int rt   = w >> 1;
    const int c0   = (w & 1) * 2;
    const int ct2b = w & 1;
    const int rowb = rg * 64 + rt * 16 + q * 4;     // + reg = global batch row
    const int nb   = cg * 32 + ct2b * 16 + cl;      // global z col
    const int clb  = ct2b * 16 + cl;                // local z col 0..31

    const size_t zbase = ((size_t)(rg * 4 + rt) * 16 + cg) * 512 +
                         (size_t)(((clb >> 3) * 16 + q * 4) * 8 + (clb & 7));
    size_t hbase[2];
#pragma unroll
    for (int c = 0; c < 2; ++c) {
        const int colc = (c0 + c) * 16 + cl;
        hbase[c] = ((size_t)(rg * 4 + rt) * 32 + cg * 2 + (colc >> 5)) * 512 +
                   (size_t)((((colc & 31) >> 3) * 16 + q * 4) * 8 + (colc & 7));
    }

    float zreg[4], kacc[4];
#pragma unroll
    for (int reg = 0; reg < 4; ++reg) {
        const float zv = z0[(size_t)(rowb + reg) * DLAT + nb];
        zreg[reg] = zv;
        traj[(size_t)(rowb + reg) * DLAT + nb] = zv;    // traj[0] exact fp32
        zf[zbase + reg * 8] = f2bf(zv);                 // direct 2B store
    }

    int target = 0;
    target += 1; rg_barrier(flg, cg, target, tid);

    const short* zrow = zf + (size_t)(rg * 4 + rt) * 8192  + lane * 8;
    const short* hrow = Hf + (size_t)(rg * 4 + rt) * 16384 + lane * 8;
    const short* w1p  = &W1L[c0 * 8192 + lane * 8];
    const short* w2p  = &W2L[ct2b * 16384 + lane * 8];

    for (int step = 0; step < TPTS - 1; ++step) {
        const float dt = t[step + 1] - t[step];

        // traj[step] hoisted: HBM stores retire under phase A, not in a drain
        if (step > 0) {
#pragma unroll
            for (int reg = 0; reg < 4; ++reg)
                traj[(size_t)step * BD + (size_t)(rowb + reg) * DLAT + nb] =
                    zreg[reg];
        }

#pragma unroll
        for (int stage = 0; stage < 4; ++stage) {
            // ============== phase A: H = tanh(z @ W1slice + b1) ==============
            {
                f32x4 acc0 = {0.f, 0.f, 0.f, 0.f};
                f32x4 acc1 = {0.f, 0.f, 0.f, 0.f};
#pragma unroll
                for (int kt = 0; kt < 16; ++kt) {
                    const short8 a  = *(const short8*)(zrow + kt * 512);
                    const short8 bA = *(const short8*)(w1p + kt * 512);
                    const short8 bB = *(const short8*)(w1p + 8192 + kt * 512);
                    acc0 = __builtin_amdgcn_mfma_f32_16x16x32_bf16(a, bA, acc0, 0, 0, 0);
                    acc1 = __builtin_amdgcn_mfma_f32_16x16x32_bf16(a, bB, acc1, 0, 0, 0);
                }
                // epilogue: bias + tanh -> DIRECT 2B stores into Hf
#pragma unroll
                for (int c = 0; c < 2; ++c) {
                    const int   cloc = (c0 + c) * 16 + cl;    // 0..63
                    const float bb   = b1L[cloc];
                    const f32x4 av   = c ? acc1 : acc0;
#pragma unroll
                    for (int reg = 0; reg < 4; ++reg)
                        Hf[hbase[c] + reg * 8] = f2bf(fast_tanh(av[reg] + bb));
                }
            }
            target += 1; rg_barrier(flg, cg, target, tid);

            // ============ phase B: kv = H @ W2slice + b2 ; RK4 update ========
            {
                f32x4 acce = {0.f, 0.f, 0.f, 0.f};
                f32x4 acco = {0.f, 0.f, 0.f, 0.f};
#pragma unroll
                for (int kt = 0; kt < 32; kt += 2) {
                    const short8 a0  = *(const short8*)(hrow + kt * 512);
                    const short8 a1  = *(const short8*)(hrow + kt * 512 + 512);
                    const short8 bb0 = *(const short8*)(w2p + kt * 512);
                    const short8 bb1 = *(const short8*)(w2p + kt * 512 + 512);
                    acce = __builtin_amdgcn_mfma_f32_16x16x32_bf16(a0, bb0, acce, 0, 0, 0);
                    acco = __builtin_amdgcn_mfma_f32_16x16x32_bf16(a1, bb1, acco, 0, 0, 0);
                }
                const float bb = b2L[clb];
#pragma unroll
                for (int reg = 0; reg < 4; ++reg) {
                    const float kv = acce[reg] + acco[reg] + bb;
                    float znext;
                    if (stage == 0) {
                        kacc[reg] = kv;        znext = zreg[reg] + 0.5f * dt * kv;
                    } else if (stage == 1) {
                        kacc[reg] += 2.f * kv; znext = zreg[reg] + 0.5f * dt * kv;
                    } else if (stage == 2) {
                        kacc[reg] += 2.f * kv; znext = zreg[reg] + dt * kv;
                    } else {
                        zreg[reg] += (dt * (1.f / 6.f)) * (kacc[reg] + kv);
                        znext = zreg[reg];
                    }
                    zf[zbase + reg * 8] = f2bf(znext);   // direct 2B store
                }
            }
            target += 1; rg_barrier(flg, cg, target, tid);
        }
    }

    // final state: traj[TPTS-1] = z_{63}
#pragma unroll
    for (int reg = 0; reg < 4; ++reg)
        traj[(size_t)(TPTS - 1) * BD + (size_t)(rowb + reg) * DLAT + nb] =
            zreg[reg];
}

// ---------------------------------------------------------------------------
extern "C" void kernel_launch(void* const* d_in, const int* in_sizes, int n_in,
                              void* d_out, int out_size, void* d_ws, size_t ws_size,
                              hipStream_t stream)
{
    (void)in_sizes; (void)n_in; (void)out_size; (void)ws_size;

    const float* z0 = (const float*)d_in[0];
    const float* t  = (const float*)d_in[1];
    const float* W1 = (const float*)d_in[2];
    const float* b1 = (const float*)d_in[3];
    const float* W2 = (const float*)d_in[4];
    const float* b2 = (const float*)d_in[5];
    float*       traj = (float*)d_out;

    // Workspace: zf (1 MB) | Hf (2 MB) | flags (4 KB) | xcnt (32 B)
    short* zf   = (short*)d_ws;
    short* Hf   = (short*)((char*)d_ws + (1u << 20));
    int*   fl   = (int*)((char*)d_ws + (3u << 20));
    int*   xcnt = (int*)((char*)d_ws + (3u << 20) + 4096);

    hipMemsetAsync(fl, 0, 4096 + 32, stream);

    void* args[] = {&z0, &t, &W1, &b1, &W2, &b2, &zf, &Hf, &fl, &xcnt, &traj};
    hipLaunchCooperativeKernel((const void*)ode_coop, dim3(NBLK), dim3(NTHR),
                               args, 0, stream);
}